// Round 1
// baseline (287.105 us; speedup 1.0000x reference)
//
#include <hip/hip_runtime.h>
#include <math.h>

#define DKD 256
#define DVD 256

constexpr int NB_MAX = 1024;   // pass-1 blocks (partials)
constexpr int TPB    = 256;    // threads per block
constexpr int WAVES  = TPB / 64;
constexpr int RG     = 64;     // pass-2 blocks

// Pass 1: each block computes an online-softmax partial over a contiguous
// chunk of KV rows: (m_b, l_b, acc_b[256]) with acc_b = sum exp(s - m_b) * V.
__global__ __launch_bounds__(TPB) void attn_pass1(
    const float* __restrict__ q,
    const float* __restrict__ K,
    const float* __restrict__ V,
    float* __restrict__ m_arr,
    float* __restrict__ l_arr,
    float* __restrict__ acc_arr,
    int M, int rows_per_block)
{
    const int lane = threadIdx.x & 63;
    const int wave = threadIdx.x >> 6;
    const int b    = blockIdx.x;

    const float4* __restrict__ K4 = (const float4*)K;
    const float4* __restrict__ V4 = (const float4*)V;
    const float4  q4 = ((const float4*)q)[lane];   // lane holds q[4*lane .. 4*lane+3]

    const int row_begin = b * rows_per_block;
    const int row_end   = min(M, row_begin + rows_per_block);

    const int per_wave = (rows_per_block + WAVES - 1) / WAVES;
    const int wbeg = row_begin + wave * per_wave;
    const int wend = min(row_end, wbeg + per_wave);

    float  mx  = -INFINITY;
    float  l   = 0.0f;
    float4 acc = make_float4(0.f, 0.f, 0.f, 0.f);

    for (int r = wbeg; r < wend; r += 4) {
        // clamp rows so loads stay in-bounds; invalid rows get s = -inf -> w = 0
        const int r0 = r;
        const int r1 = min(r + 1, wend - 1);
        const int r2 = min(r + 2, wend - 1);
        const int r3 = min(r + 3, wend - 1);
        const bool v1 = (r + 1 < wend), v2 = (r + 2 < wend), v3 = (r + 3 < wend);

        float4 k0 = K4[(size_t)r0 * 64 + lane];
        float4 k1 = K4[(size_t)r1 * 64 + lane];
        float4 k2 = K4[(size_t)r2 * 64 + lane];
        float4 k3 = K4[(size_t)r3 * 64 + lane];
        float4 w0v = V4[(size_t)r0 * 64 + lane];
        float4 w1v = V4[(size_t)r1 * 64 + lane];
        float4 w2v = V4[(size_t)r2 * 64 + lane];
        float4 w3v = V4[(size_t)r3 * 64 + lane];

        float s0 = k0.x*q4.x + k0.y*q4.y + k0.z*q4.z + k0.w*q4.w;
        float s1 = k1.x*q4.x + k1.y*q4.y + k1.z*q4.z + k1.w*q4.w;
        float s2 = k2.x*q4.x + k2.y*q4.y + k2.z*q4.z + k2.w*q4.w;
        float s3 = k3.x*q4.x + k3.y*q4.y + k3.z*q4.z + k3.w*q4.w;

        // wave-64 allreduce (4 independent chains pipeline through the DS unit)
        #pragma unroll
        for (int off = 32; off > 0; off >>= 1) {
            s0 += __shfl_xor(s0, off);
            s1 += __shfl_xor(s1, off);
            s2 += __shfl_xor(s2, off);
            s3 += __shfl_xor(s3, off);
        }

        if (!v1) s1 = -INFINITY;
        if (!v2) s2 = -INFINITY;
        if (!v3) s3 = -INFINITY;

        const float nm = fmaxf(mx, fmaxf(fmaxf(s0, s1), fmaxf(s2, s3)));
        const float corr = __expf(mx - nm);
        const float e0 = __expf(s0 - nm);
        const float e1 = __expf(s1 - nm);
        const float e2 = __expf(s2 - nm);
        const float e3 = __expf(s3 - nm);

        l = l * corr + (e0 + e1 + e2 + e3);
        acc.x = acc.x * corr + e0*w0v.x + e1*w1v.x + e2*w2v.x + e3*w3v.x;
        acc.y = acc.y * corr + e0*w0v.y + e1*w1v.y + e2*w2v.y + e3*w3v.y;
        acc.z = acc.z * corr + e0*w0v.z + e1*w1v.z + e2*w2v.z + e3*w3v.z;
        acc.w = acc.w * corr + e0*w0v.w + e1*w1v.w + e2*w2v.w + e3*w3v.w;
        mx = nm;
    }

    // combine the block's WAVES partials in LDS
    __shared__ float4 s_acc[WAVES][64];
    __shared__ float  s_mx[WAVES];
    __shared__ float  s_l[WAVES];

    s_acc[wave][lane] = acc;
    if (lane == 0) { s_mx[wave] = mx; s_l[wave] = l; }
    __syncthreads();

    const int t = threadIdx.x;   // t = output dim index 0..255
    float bm = -INFINITY;
    #pragma unroll
    for (int w = 0; w < WAVES; ++w) bm = fmaxf(bm, s_mx[w]);
    if (bm == -INFINITY) bm = 0.0f;   // degenerate empty block

    float yv = 0.0f, bl = 0.0f;
    const float* s_acc_f = (const float*)&s_acc[0][0];
    #pragma unroll
    for (int w = 0; w < WAVES; ++w) {
        const float sc = __expf(s_mx[w] - bm);
        yv += sc * s_acc_f[w * DVD + t];
        bl += sc * s_l[w];
    }

    acc_arr[(size_t)b * DVD + t] = yv;
    if (t == 0) { m_arr[b] = bm; l_arr[b] = bl; }
}

// Pass 2: combine nb partials.  Every block redundantly computes the global
// max and denominator (tiny, L2-hot), then reduces its slice of acc partials
// and atomically adds into out (zeroed by a memset node).
__global__ __launch_bounds__(256) void attn_pass2(
    const float* __restrict__ m_arr,
    const float* __restrict__ l_arr,
    const float* __restrict__ acc_arr,
    float* __restrict__ out,
    int nb, int chunk)
{
    __shared__ float red[256];
    __shared__ float sscale[64];
    const int t = threadIdx.x;

    // global max of m_arr
    float lm = -INFINITY;
    for (int b = t; b < nb; b += 256) lm = fmaxf(lm, m_arr[b]);
    red[t] = lm; __syncthreads();
    for (int s = 128; s > 0; s >>= 1) {
        if (t < s) red[t] = fmaxf(red[t], red[t + s]);
        __syncthreads();
    }
    const float Mg = red[0];
    __syncthreads();

    // global denominator
    float ll = 0.0f;
    for (int b = t; b < nb; b += 256) ll += l_arr[b] * __expf(m_arr[b] - Mg);
    red[t] = ll; __syncthreads();
    for (int s = 128; s > 0; s >>= 1) {
        if (t < s) red[t] += red[t + s];
        __syncthreads();
    }
    const float invL = 1.0f / red[0];
    __syncthreads();

    const int b0 = blockIdx.x * chunk;
    const int b1 = min(nb, b0 + chunk);
    if (t < b1 - b0) sscale[t] = __expf(m_arr[b0 + t] - Mg);
    __syncthreads();

    float part = 0.0f;
    for (int b = b0; b < b1; ++b)
        part += sscale[b - b0] * acc_arr[(size_t)b * DVD + t];

    atomicAdd(&out[t], part * invL);
}

extern "C" void kernel_launch(void* const* d_in, const int* in_sizes, int n_in,
                              void* d_out, int out_size, void* d_ws, size_t ws_size,
                              hipStream_t stream) {
    const float* q = (const float*)d_in[0];
    const float* K = (const float*)d_in[1];
    const float* V = (const float*)d_in[2];
    float* out = (float*)d_out;

    const int M = in_sizes[1] / DKD;

    // workspace layout: m[nb] | l[nb] | acc[nb*256]
    int nb = NB_MAX;
    while (nb > 1 && (size_t)nb * (2 + DVD) * sizeof(float) > ws_size) nb >>= 1;
    float* ws     = (float*)d_ws;
    float* m_arr  = ws;
    float* l_arr  = ws + nb;
    float* acc_arr= ws + 2 * nb;

    const int rpb = (M + nb - 1) / nb;

    hipMemsetAsync(d_out, 0, DVD * sizeof(float), stream);
    attn_pass1<<<nb, TPB, 0, stream>>>(q, K, V, m_arr, l_arr, acc_arr, M, rpb);
    const int chunk = (nb + RG - 1) / RG;   // <= 64, fits sscale
    attn_pass2<<<RG, 256, 0, stream>>>(m_arr, l_arr, acc_arr, out, nb, chunk);
}

// Round 2
// 286.683 us; speedup vs baseline: 1.0015x; 1.0015x over previous
//
#include <hip/hip_runtime.h>
#include <math.h>

#define DKD 256
#define DVD 256

constexpr int NB_MAX = 2048;   // pass-1 blocks (partials); 8 blocks/CU on 256 CUs
constexpr int TPB    = 256;    // threads per block
constexpr int WAVES  = TPB / 64;

// Pass 1: each block computes an online-softmax partial over a contiguous
// chunk of KV rows: (m_b, l_b, acc_b[256]) with acc_b = sum exp(s - m_b) * V.
// __launch_bounds__(256,8): 8 workgroups/CU => 32 waves/CU, caps VGPR <= 64.
__global__ __launch_bounds__(TPB, 8) void attn_pass1(
    const float* __restrict__ q,
    const float* __restrict__ K,
    const float* __restrict__ V,
    float* __restrict__ m_arr,
    float* __restrict__ l_arr,
    float* __restrict__ acc_arr,
    int M, int rows_per_block)
{
    const int lane = threadIdx.x & 63;
    const int wave = threadIdx.x >> 6;
    const int b    = blockIdx.x;

    const float4* __restrict__ K4 = (const float4*)K;
    const float4* __restrict__ V4 = (const float4*)V;
    const float4  q4 = ((const float4*)q)[lane];   // lane holds q[4*lane .. 4*lane+3]

    const int row_begin = b * rows_per_block;
    const int row_end   = min(M, row_begin + rows_per_block);

    const int per_wave = (rows_per_block + WAVES - 1) / WAVES;
    const int wbeg = row_begin + wave * per_wave;
    const int wend = min(row_end, wbeg + per_wave);

    float  mx  = -INFINITY;
    float  l   = 0.0f;
    float4 acc = make_float4(0.f, 0.f, 0.f, 0.f);

    // main loop: exact groups of 4 rows, no clamping (M=131072 divides evenly)
    const int n_rows = wend - wbeg;
    const int full_end = wbeg + (n_rows & ~3);

    for (int r = wbeg; r < full_end; r += 4) {
        const size_t base = (size_t)r * 64 + lane;
        float4 k0 = K4[base];
        float4 k1 = K4[base + 64];
        float4 k2 = K4[base + 128];
        float4 k3 = K4[base + 192];
        float4 v0 = V4[base];
        float4 v1 = V4[base + 64];
        float4 v2 = V4[base + 128];
        float4 v3 = V4[base + 192];

        float s0 = k0.x*q4.x + k0.y*q4.y + k0.z*q4.z + k0.w*q4.w;
        float s1 = k1.x*q4.x + k1.y*q4.y + k1.z*q4.z + k1.w*q4.w;
        float s2 = k2.x*q4.x + k2.y*q4.y + k2.z*q4.z + k2.w*q4.w;
        float s3 = k3.x*q4.x + k3.y*q4.y + k3.z*q4.z + k3.w*q4.w;

        #pragma unroll
        for (int off = 32; off > 0; off >>= 1) {
            s0 += __shfl_xor(s0, off);
            s1 += __shfl_xor(s1, off);
            s2 += __shfl_xor(s2, off);
            s3 += __shfl_xor(s3, off);
        }

        const float nm = fmaxf(mx, fmaxf(fmaxf(s0, s1), fmaxf(s2, s3)));
        const float corr = __expf(mx - nm);
        const float e0 = __expf(s0 - nm);
        const float e1 = __expf(s1 - nm);
        const float e2 = __expf(s2 - nm);
        const float e3 = __expf(s3 - nm);

        l = l * corr + (e0 + e1 + e2 + e3);
        acc.x = acc.x * corr + e0*v0.x + e1*v1.x + e2*v2.x + e3*v3.x;
        acc.y = acc.y * corr + e0*v0.y + e1*v1.y + e2*v2.y + e3*v3.y;
        acc.z = acc.z * corr + e0*v0.z + e1*v1.z + e2*v2.z + e3*v3.z;
        acc.w = acc.w * corr + e0*v0.w + e1*v1.w + e2*v2.w + e3*v3.w;
        mx = nm;
    }

    // tail (never taken for the bench shape, kept for generality)
    for (int r = full_end; r < wend; ++r) {
        float4 k0 = K4[(size_t)r * 64 + lane];
        float4 v0 = V4[(size_t)r * 64 + lane];
        float s0 = k0.x*q4.x + k0.y*q4.y + k0.z*q4.z + k0.w*q4.w;
        #pragma unroll
        for (int off = 32; off > 0; off >>= 1) s0 += __shfl_xor(s0, off);
        const float nm = fmaxf(mx, s0);
        const float corr = __expf(mx - nm);
        const float e0 = __expf(s0 - nm);
        l = l * corr + e0;
        acc.x = acc.x * corr + e0*v0.x;
        acc.y = acc.y * corr + e0*v0.y;
        acc.z = acc.z * corr + e0*v0.z;
        acc.w = acc.w * corr + e0*v0.w;
        mx = nm;
    }

    // combine the block's WAVES partials in LDS
    __shared__ float4 s_acc[WAVES][64];
    __shared__ float  s_mx[WAVES];
    __shared__ float  s_l[WAVES];

    s_acc[wave][lane] = acc;
    if (lane == 0) { s_mx[wave] = mx; s_l[wave] = l; }
    __syncthreads();

    const int t = threadIdx.x;   // t = output dim index 0..255
    float bm = -INFINITY;
    #pragma unroll
    for (int w = 0; w < WAVES; ++w) bm = fmaxf(bm, s_mx[w]);
    if (bm == -INFINITY) bm = 0.0f;   // degenerate empty block

    float yv = 0.0f, bl = 0.0f;
    const float* s_acc_f = (const float*)&s_acc[0][0];
    #pragma unroll
    for (int w = 0; w < WAVES; ++w) {
        const float sc = __expf(s_mx[w] - bm);
        yv += sc * s_acc_f[w * DVD + t];
        bl += sc * s_l[w];
    }

    acc_arr[(size_t)b * DVD + t] = yv;
    if (t == 0) { m_arr[b] = bm; l_arr[b] = bl; }
}

// Pass 2: deterministic combine, no atomics, no memset. Block j computes
// out[j]. Every block redundantly computes global max + denominator from the
// tiny (m,l) arrays (L2/L3-hot), then reduces column j of the partials.
__global__ __launch_bounds__(256) void attn_pass2(
    const float* __restrict__ m_arr,
    const float* __restrict__ l_arr,
    const float* __restrict__ acc_arr,
    float* __restrict__ out,
    int nb)
{
    __shared__ float red[256];
    __shared__ float sscale[NB_MAX];
    const int t = threadIdx.x;

    // global max of m_arr
    float lm = -INFINITY;
    for (int b = t; b < nb; b += 256) lm = fmaxf(lm, m_arr[b]);
    red[t] = lm; __syncthreads();
    for (int s = 128; s > 0; s >>= 1) {
        if (t < s) red[t] = fmaxf(red[t], red[t + s]);
        __syncthreads();
    }
    const float Mg = red[0];
    __syncthreads();

    // global denominator + per-partial scales
    float ll = 0.0f;
    for (int b = t; b < nb; b += 256) {
        const float sc = __expf(m_arr[b] - Mg);
        sscale[b] = sc;
        ll += sc * l_arr[b];
    }
    red[t] = ll; __syncthreads();
    for (int s = 128; s > 0; s >>= 1) {
        if (t < s) red[t] += red[t + s];
        __syncthreads();
    }
    const float invL = 1.0f / red[0];
    __syncthreads();

    // column-j reduction over nb partials (thread t wrote sscale[b] for the
    // same b values it reads here — no cross-thread hazard)
    const int j = blockIdx.x;
    float part = 0.0f;
    for (int b = t; b < nb; b += 256)
        part += sscale[b] * acc_arr[(size_t)b * DVD + j];

    red[t] = part; __syncthreads();
    for (int s = 128; s > 0; s >>= 1) {
        if (t < s) red[t] += red[t + s];
        __syncthreads();
    }
    if (t == 0) out[j] = red[0] * invL;
}

extern "C" void kernel_launch(void* const* d_in, const int* in_sizes, int n_in,
                              void* d_out, int out_size, void* d_ws, size_t ws_size,
                              hipStream_t stream) {
    const float* q = (const float*)d_in[0];
    const float* K = (const float*)d_in[1];
    const float* V = (const float*)d_in[2];
    float* out = (float*)d_out;

    const int M = in_sizes[1] / DKD;

    // workspace layout: m[nb] | l[nb] | acc[nb*256]
    int nb = NB_MAX;
    while (nb > 1 && (size_t)nb * (2 + DVD) * sizeof(float) > ws_size) nb >>= 1;
    float* ws      = (float*)d_ws;
    float* m_arr   = ws;
    float* l_arr   = ws + nb;
    float* acc_arr = ws + 2 * nb;

    const int rpb = (M + nb - 1) / nb;

    attn_pass1<<<nb, TPB, 0, stream>>>(q, K, V, m_arr, l_arr, acc_arr, M, rpb);
    attn_pass2<<<DVD, 256, 0, stream>>>(m_arr, l_arr, acc_arr, out, nb);
}

// Round 3
// 283.256 us; speedup vs baseline: 1.0136x; 1.0121x over previous
//
#include <hip/hip_runtime.h>
#include <math.h>

#define DKD 256
#define DVD 256

constexpr int RPB   = 128;   // rows per pass-1 block
constexpr int TPB   = 256;
constexpr int WAVES = TPB / 64;

// Pass 1, restructured: block-local (non-online) softmax partial.
//  Phase A: 256 threads compute 128 logits (thread t owns half-row t&127,
//           half t>>7) — no wave shuffles, 32 independent float4 loads/thread.
//  LDS trees: block max, exp, denominator (once per block, off hot path).
//  Phase B: weighted V sum with weights broadcast from LDS — loop body is
//           8 independent 1KiB loads + FMAs. No exp/rescale/shuffle in loop.
// __launch_bounds__(256,4): 4 blocks/CU (nb=1024 => exactly resident),
// VGPR cap 128 so the compiler can keep 8+ loads in flight.
__global__ __launch_bounds__(TPB, 4) void attn_pass1(
    const float* __restrict__ q,
    const float* __restrict__ K,
    const float* __restrict__ V,
    float* __restrict__ m_arr,
    float* __restrict__ l_arr,
    float* __restrict__ acc_arr,
    int M)
{
    __shared__ float  q_lds[DKD];
    __shared__ float  part[2][RPB];
    __shared__ float  e_lds[RPB];
    __shared__ float  red[RPB];
    __shared__ float4 s_acc[WAVES][64];
    __shared__ float  s_l;

    const int t    = threadIdx.x;
    const int lane = t & 63;
    const int wave = t >> 6;
    const int b    = blockIdx.x;
    const int row_begin = b * RPB;

    q_lds[t] = q[t];           // DKD == TPB == 256
    __syncthreads();

    const float4* __restrict__ K4  = (const float4*)K;
    const float4* __restrict__ V4  = (const float4*)V;
    const float4* q4l = (const float4*)q_lds;

    // ---- Phase A: half-row dot products ----
    const int rowA  = t & (RPB - 1);
    const int halfA = t >> 7;                       // 0 or 1
    const int growc = min(row_begin + rowA, M - 1); // clamped for safety

    float4 d = make_float4(0.f, 0.f, 0.f, 0.f);
    const size_t kbase = (size_t)growc * (DKD / 4) + halfA * (DKD / 8);
    #pragma unroll 8
    for (int j = 0; j < DKD / 8; ++j) {
        const float4 kv = K4[kbase + j];
        const float4 qv = q4l[halfA * (DKD / 8) + j];   // wave-uniform LDS read
        d.x += kv.x * qv.x; d.y += kv.y * qv.y;
        d.z += kv.z * qv.z; d.w += kv.w * qv.w;
    }
    part[halfA][rowA] = d.x + d.y + d.z + d.w;
    __syncthreads();

    // ---- block max / exp / denominator ----
    float logit = 0.f;
    if (t < RPB) {
        logit = part[0][t] + part[1][t];
        if (row_begin + t >= M) logit = -INFINITY;
        red[t] = logit;
    }
    __syncthreads();
    #pragma unroll
    for (int s = RPB / 2; s > 0; s >>= 1) {
        if (t < s) red[t] = fmaxf(red[t], red[t + s]);
        __syncthreads();
    }
    float bm = red[0];
    if (bm == -INFINITY) bm = 0.f;
    __syncthreads();
    if (t < RPB) {
        float e = __expf(logit - bm);
        if (row_begin + t >= M) e = 0.f;
        e_lds[t] = e;
        red[t] = e;
    }
    __syncthreads();
    #pragma unroll
    for (int s = RPB / 2; s > 0; s >>= 1) {
        if (t < s) red[t] += red[t + s];
        __syncthreads();
    }
    if (t == 0) s_l = red[0];

    // ---- Phase B: acc += e[r] * V[r,:], wave w owns rows [w*32, w*32+32) ----
    float4 acc = make_float4(0.f, 0.f, 0.f, 0.f);
    const int rw = wave * (RPB / WAVES);
    for (int it = 0; it < (RPB / WAVES) / 8; ++it) {
        const int r0 = rw + it * 8;
        #pragma unroll
        for (int u = 0; u < 8; ++u) {
            const int rl = r0 + u;
            const int gv = min(row_begin + rl, M - 1);      // wave-uniform
            const float  e  = e_lds[rl];                    // LDS broadcast
            const float4 vv = V4[(size_t)gv * (DVD / 4) + lane];
            acc.x += e * vv.x; acc.y += e * vv.y;
            acc.z += e * vv.z; acc.w += e * vv.w;
        }
    }
    s_acc[wave][lane] = acc;
    __syncthreads();

    float yv = 0.f;
    const float* saf = (const float*)&s_acc[0][0];
    #pragma unroll
    for (int w = 0; w < WAVES; ++w) yv += saf[w * DVD + t];
    acc_arr[(size_t)b * DVD + t] = yv;
    if (t == 0) { m_arr[b] = bm; l_arr[b] = s_l; }
}

// Pass 2: deterministic combine. Block j computes out[j]; every block
// redundantly computes global max + denominator from the tiny (m,l) arrays.
__global__ __launch_bounds__(256) void attn_pass2(
    const float* __restrict__ m_arr,
    const float* __restrict__ l_arr,
    const float* __restrict__ acc_arr,
    float* __restrict__ out,
    int nb)
{
    __shared__ float red[256];
    const int t = threadIdx.x;

    float lm = -INFINITY;
    for (int b = t; b < nb; b += 256) lm = fmaxf(lm, m_arr[b]);
    red[t] = lm; __syncthreads();
    for (int s = 128; s > 0; s >>= 1) {
        if (t < s) red[t] = fmaxf(red[t], red[t + s]);
        __syncthreads();
    }
    const float Mg = red[0];
    __syncthreads();

    float ll = 0.0f;
    for (int b = t; b < nb; b += 256) ll += l_arr[b] * __expf(m_arr[b] - Mg);
    red[t] = ll; __syncthreads();
    for (int s = 128; s > 0; s >>= 1) {
        if (t < s) red[t] += red[t + s];
        __syncthreads();
    }
    const float invL = 1.0f / red[0];
    __syncthreads();

    const int j = blockIdx.x;
    float part = 0.0f;
    for (int b = t; b < nb; b += 256)
        part += __expf(m_arr[b] - Mg) * acc_arr[(size_t)b * DVD + j];

    red[t] = part; __syncthreads();
    for (int s = 128; s > 0; s >>= 1) {
        if (t < s) red[t] += red[t + s];
        __syncthreads();
    }
    if (t == 0) out[j] = red[0] * invL;
}

extern "C" void kernel_launch(void* const* d_in, const int* in_sizes, int n_in,
                              void* d_out, int out_size, void* d_ws, size_t ws_size,
                              hipStream_t stream) {
    const float* q = (const float*)d_in[0];
    const float* K = (const float*)d_in[1];
    const float* V = (const float*)d_in[2];
    float* out = (float*)d_out;

    const int M  = in_sizes[1] / DKD;
    const int nb = (M + RPB - 1) / RPB;   // 1024 for M=131072

    // workspace layout: m[nb] | l[nb] | acc[nb*256]  (~1.06 MB)
    float* ws      = (float*)d_ws;
    float* m_arr   = ws;
    float* l_arr   = ws + nb;
    float* acc_arr = ws + 2 * nb;

    attn_pass1<<<nb, TPB, 0, stream>>>(q, K, V, m_arr, l_arr, acc_arr, M);
    attn_pass2<<<DVD, 256, 0, stream>>>(m_arr, l_arr, acc_arr, out, nb);
}

// Round 4
// 280.570 us; speedup vs baseline: 1.0233x; 1.0096x over previous
//
#include <hip/hip_runtime.h>
#include <math.h>

#define DKD 256
#define DVD 256

constexpr int RPB    = 256;            // rows per pass-1 block
constexpr int TILE_R = 32;             // rows per LDS tile (32 KB)
constexpr int NTILES = RPB / TILE_R;   // 8 tiles per phase
constexpr int TPB    = 256;
constexpr int WAVES  = 4;

// Async global->LDS DMA, 16 B per lane. No VGPR destination => a wave can
// keep 8+ of these in flight regardless of register allocation. Lane i's
// 16 B land at ldsbase + i*16 (wave-uniform base + lane*size scatter).
__device__ __forceinline__ void async_row16(const float* g, float* l) {
    __builtin_amdgcn_global_load_lds(
        (const __attribute__((address_space(1))) void*)g,
        (__attribute__((address_space(3))) void*)l,
        16, 0, 0);
}

// Each wave stages its 8 rows of a 32-row tile: 8 back-to-back 1 KiB DMAs.
__device__ __forceinline__ void stage_tile(const float* __restrict__ src,
                                           int g_row0, int M,
                                           float* lbuf, int wave, int lane) {
    #pragma unroll
    for (int i = 0; i < TILE_R / WAVES; ++i) {
        const int lrow = wave * (TILE_R / WAVES) + i;
        int grow = g_row0 + lrow;
        grow = grow < M ? grow : M - 1;            // clamp (general M); e=0 later
        async_row16(src + (size_t)grow * DKD + lane * 4,
                    lbuf + lrow * DKD);
    }
}

// Pass 1: block-local softmax partial over 256 rows, streamed through LDS.
//   Phase K: logits for 32-row tiles; thread = (row, 8-lane segment),
//            8x (ds_read_b128 K + broadcast q) + 3 shuffles per tile.
//   Softmax: 256-wide LDS trees (max, exp, sum) once per block.
//   Phase V: acc4 += e[r] * V[r,:] from LDS tiles; no exp/shuffle in loop.
// LDS: 2x32KB tiles + ~7KB scratch = 71KB -> 2 blocks/CU (launch_bounds(256,2)).
__global__ __launch_bounds__(TPB, 2) void attn_pass1(
    const float* __restrict__ q,
    const float* __restrict__ K,
    const float* __restrict__ V,
    float* __restrict__ m_arr,
    float* __restrict__ l_arr,
    float* __restrict__ acc_arr,
    int M)
{
    __shared__ float  buf[2][TILE_R * DKD];   // 2 x 32 KB
    __shared__ float  q_lds[DKD];
    __shared__ float  e_lds[RPB];             // logits, then exp weights
    __shared__ float  red[TPB];
    __shared__ float4 s_acc[WAVES][64];
    __shared__ float  s_l;

    const int t    = threadIdx.x;
    const int lane = t & 63;
    const int wave = t >> 6;
    const int b    = blockIdx.x;
    const int row_begin = b * RPB;

    q_lds[t] = q[t];                          // DKD == TPB
    stage_tile(K, row_begin, M, buf[0], wave, lane);

    // ---- Phase K: logits ----
    const int seg  = lane & 7;                // 8-lane segment of a row
    const int rsub = lane >> 3;               // row within wave's 8-row slice
    for (int kt = 0; kt < NTILES; ++kt) {
        __syncthreads();                      // tile kt ready (vmcnt drain)
        if (kt + 1 < NTILES)
            stage_tile(K, row_begin + (kt + 1) * TILE_R, M, buf[(kt + 1) & 1], wave, lane);
        else
            stage_tile(V, row_begin, M, buf[NTILES & 1], wave, lane);  // prefetch V0

        const int rloc = wave * 8 + rsub;     // row 0..31 in tile
        const float4* krow = (const float4*)(buf[kt & 1] + rloc * DKD);
        const float4* q4   = (const float4*)q_lds;
        float4 d = make_float4(0.f, 0.f, 0.f, 0.f);
        #pragma unroll
        for (int j = 0; j < 8; ++j) {
            // interleaved segment mapping: float4 index seg + 8j spreads the
            // 8 segments across all 32 banks (8-way alias max, not 16-way)
            const float4 kv = krow[seg + 8 * j];
            const float4 qv = q4[seg + 8 * j];    // broadcast within seg group
            d.x += kv.x * qv.x; d.y += kv.y * qv.y;
            d.z += kv.z * qv.z; d.w += kv.w * qv.w;
        }
        float s = d.x + d.y + d.z + d.w;
        s += __shfl_xor(s, 1);
        s += __shfl_xor(s, 2);
        s += __shfl_xor(s, 4);
        if (seg == 0) e_lds[kt * TILE_R + rloc] = s;
    }

    // ---- block softmax over 256 logits (V0 DMA drains under these barriers) ----
    __syncthreads();
    float logit = e_lds[t];
    if (row_begin + t >= M) logit = -INFINITY;
    red[t] = logit;
    __syncthreads();
    #pragma unroll
    for (int s = 128; s > 0; s >>= 1) {
        if (t < s) red[t] = fmaxf(red[t], red[t + s]);
        __syncthreads();
    }
    float bm = red[0];
    if (bm == -INFINITY) bm = 0.f;
    __syncthreads();
    const float e = (row_begin + t < M) ? __expf(logit - bm) : 0.f;
    e_lds[t] = e;
    red[t]   = e;
    __syncthreads();
    #pragma unroll
    for (int s = 128; s > 0; s >>= 1) {
        if (t < s) red[t] += red[t + s];
        __syncthreads();
    }
    if (t == 0) s_l = red[0];

    // ---- Phase V: weighted V accumulation ----
    float4 acc = make_float4(0.f, 0.f, 0.f, 0.f);
    for (int vt = 0; vt < NTILES; ++vt) {
        __syncthreads();                      // V tile vt ready; e_lds visible
        if (vt + 1 < NTILES)
            stage_tile(V, row_begin + (vt + 1) * TILE_R, M,
                       buf[(NTILES + vt + 1) & 1], wave, lane);

        const float* vb = buf[(NTILES + vt) & 1];
        #pragma unroll
        for (int u = 0; u < 8; ++u) {
            const int rloc = wave * 8 + u;
            const float  ew = e_lds[vt * TILE_R + rloc];    // LDS broadcast
            const float4 vv = ((const float4*)vb)[rloc * 64 + lane];
            acc.x += ew * vv.x; acc.y += ew * vv.y;
            acc.z += ew * vv.z; acc.w += ew * vv.w;
        }
    }

    s_acc[wave][lane] = acc;
    __syncthreads();
    float yv = 0.f;
    const float* saf = (const float*)&s_acc[0][0];
    #pragma unroll
    for (int w = 0; w < WAVES; ++w) yv += saf[w * DVD + t];
    acc_arr[(size_t)b * DVD + t] = yv;
    if (t == 0) { m_arr[b] = bm; l_arr[b] = s_l; }
}

// Pass 2: deterministic combine. Block j computes out[j]; every block
// redundantly computes global max + denominator from the tiny (m,l) arrays.
__global__ __launch_bounds__(256) void attn_pass2(
    const float* __restrict__ m_arr,
    const float* __restrict__ l_arr,
    const float* __restrict__ acc_arr,
    float* __restrict__ out,
    int nb)
{
    __shared__ float red[256];
    const int t = threadIdx.x;

    float lm = -INFINITY;
    for (int b = t; b < nb; b += 256) lm = fmaxf(lm, m_arr[b]);
    red[t] = lm; __syncthreads();
    for (int s = 128; s > 0; s >>= 1) {
        if (t < s) red[t] = fmaxf(red[t], red[t + s]);
        __syncthreads();
    }
    const float Mg = red[0];
    __syncthreads();

    float ll = 0.0f;
    for (int b = t; b < nb; b += 256) ll += l_arr[b] * __expf(m_arr[b] - Mg);
    red[t] = ll; __syncthreads();
    for (int s = 128; s > 0; s >>= 1) {
        if (t < s) red[t] += red[t + s];
        __syncthreads();
    }
    const float invL = 1.0f / red[0];
    __syncthreads();

    const int j = blockIdx.x;
    float part = 0.0f;
    for (int b = t; b < nb; b += 256)
        part += __expf(m_arr[b] - Mg) * acc_arr[(size_t)b * DVD + j];

    red[t] = part; __syncthreads();
    for (int s = 128; s > 0; s >>= 1) {
        if (t < s) red[t] += red[t + s];
        __syncthreads();
    }
    if (t == 0) out[j] = red[0] * invL;
}

extern "C" void kernel_launch(void* const* d_in, const int* in_sizes, int n_in,
                              void* d_out, int out_size, void* d_ws, size_t ws_size,
                              hipStream_t stream) {
    const float* q = (const float*)d_in[0];
    const float* K = (const float*)d_in[1];
    const float* V = (const float*)d_in[2];
    float* out = (float*)d_out;

    const int M  = in_sizes[1] / DKD;
    const int nb = (M + RPB - 1) / RPB;   // 512 for M=131072

    // workspace layout: m[nb] | l[nb] | acc[nb*256]  (~530 KB)
    float* ws      = (float*)d_ws;
    float* m_arr   = ws;
    float* l_arr   = ws + nb;
    float* acc_arr = ws + 2 * nb;

    attn_pass1<<<nb, TPB, 0, stream>>>(q, K, V, m_arr, l_arr, acc_arr, M);
    attn_pass2<<<DVD, 256, 0, stream>>>(m_arr, l_arr, acc_arr, out, nb);
}

// Round 6
// 265.273 us; speedup vs baseline: 1.0823x; 1.0577x over previous
//
#include <hip/hip_runtime.h>
#include <math.h>

#define DKD 256
#define DVD 256

constexpr int TPB   = 256;
constexpr int NB    = 1024;   // blocks for the two streaming kernels (4/CU)
constexpr int RPB   = 128;    // rows per block (M = 131072)
constexpr int RED_B = 64;     // blocks for the logit reductions

typedef float floatx4 __attribute__((ext_vector_type(4)));

__device__ __forceinline__ float4 ntload4(const float4* p) {
    floatx4 v = __builtin_nontemporal_load((const floatx4*)p);
    return make_float4(v.x, v.y, v.z, v.w);
}

// ---- Kernel A: logits[r] = K[r,:] . q  (reads only K; pure stream) ----
__global__ __launch_bounds__(TPB, 4) void k_logits(
    const float* __restrict__ q,
    const float* __restrict__ K,
    float* __restrict__ logits,
    int M)
{
    const int lane = threadIdx.x & 63;
    const int wave = threadIdx.x >> 6;
    const float4* __restrict__ K4 = (const float4*)K;
    const float4 q4 = ((const float4*)q)[lane];

    const int wbeg = blockIdx.x * RPB + wave * (RPB / 4);   // 32 rows per wave

    #pragma unroll 2
    for (int it = 0; it < (RPB / 4) / 4; ++it) {            // 8 iters x 4 rows
        const int r = wbeg + it * 4;
        if (r >= M) break;
        const size_t base = (size_t)r * 64 + lane;
        float4 k0 = ntload4(&K4[base]);
        float4 k1 = ntload4(&K4[base + 64]);
        float4 k2 = ntload4(&K4[base + 128]);
        float4 k3 = ntload4(&K4[base + 192]);

        float s0 = k0.x*q4.x + k0.y*q4.y + k0.z*q4.z + k0.w*q4.w;
        float s1 = k1.x*q4.x + k1.y*q4.y + k1.z*q4.z + k1.w*q4.w;
        float s2 = k2.x*q4.x + k2.y*q4.y + k2.z*q4.z + k2.w*q4.w;
        float s3 = k3.x*q4.x + k3.y*q4.y + k3.z*q4.z + k3.w*q4.w;

        #pragma unroll
        for (int off = 32; off > 0; off >>= 1) {
            s0 += __shfl_xor(s0, off);
            s1 += __shfl_xor(s1, off);
            s2 += __shfl_xor(s2, off);
            s3 += __shfl_xor(s3, off);
        }
        if (lane < 4) {
            const float sv = lane == 0 ? s0 : lane == 1 ? s1 : lane == 2 ? s2 : s3;
            if (r + lane < M) logits[r + lane] = sv;
        }
    }
}

// ---- Kernel Bmax: per-block partial max of logits ----
__global__ __launch_bounds__(TPB) void k_max(
    const float* __restrict__ logits, float* __restrict__ pmax, int M)
{
    __shared__ float red[TPB];
    const int t = threadIdx.x;
    const float4* L4 = (const float4*)logits;
    const int n4 = M / 4;
    float lm = -INFINITY;
    for (int i = blockIdx.x * TPB + t; i < n4; i += RED_B * TPB) {
        const float4 v = L4[i];
        lm = fmaxf(lm, fmaxf(fmaxf(v.x, v.y), fmaxf(v.z, v.w)));
    }
    red[t] = lm; __syncthreads();
    for (int s = TPB / 2; s > 0; s >>= 1) {
        if (t < s) red[t] = fmaxf(red[t], red[t + s]);
        __syncthreads();
    }
    if (t == 0) pmax[blockIdx.x] = red[0];
}

// ---- Kernel Bsum: w[r] = exp(logit[r]-Mg); per-block partial sum ----
__global__ __launch_bounds__(TPB) void k_expsum(
    const float* __restrict__ logits,
    const float* __restrict__ pmax,
    float* __restrict__ w,
    float* __restrict__ psum,
    int M)
{
    __shared__ float red[TPB];
    const int t = threadIdx.x;

    float lm = (t < RED_B) ? pmax[t] : -INFINITY;
    red[t] = lm; __syncthreads();
    for (int s = TPB / 2; s > 0; s >>= 1) {
        if (t < s) red[t] = fmaxf(red[t], red[t + s]);
        __syncthreads();
    }
    const float Mg = red[0];
    __syncthreads();

    const float4* L4 = (const float4*)logits;
    float4* W4 = (float4*)w;
    const int n4 = M / 4;
    float ls = 0.f;
    for (int i = blockIdx.x * TPB + t; i < n4; i += RED_B * TPB) {
        const float4 v = L4[i];
        float4 e;
        e.x = __expf(v.x - Mg); e.y = __expf(v.y - Mg);
        e.z = __expf(v.z - Mg); e.w = __expf(v.w - Mg);
        W4[i] = e;
        ls += e.x + e.y + e.z + e.w;
    }
    red[t] = ls; __syncthreads();
    for (int s = TPB / 2; s > 0; s >>= 1) {
        if (t < s) red[t] += red[t + s];
        __syncthreads();
    }
    if (t == 0) psum[blockIdx.x] = red[0];
}

// ---- Kernel C: partT[j][b] = sum_{r in block b} w[r] * V[r,j] ----
// Reads only V (pure stream) + tiny w broadcasts. No exp/shuffle in loop.
__global__ __launch_bounds__(TPB, 4) void k_vacc(
    const float* __restrict__ V,
    const float* __restrict__ w,
    float* __restrict__ partT,   // [DVD][NB], transposed for kernel D
    int M)
{
    __shared__ float4 s_acc[4][64];
    const int t    = threadIdx.x;
    const int lane = t & 63;
    const int wave = t >> 6;
    const int b    = blockIdx.x;
    const float4* __restrict__ V4 = (const float4*)V;
    const float4* __restrict__ W4 = (const float4*)w;

    const int wbeg = b * RPB + wave * (RPB / 4);
    float4 acc = make_float4(0.f, 0.f, 0.f, 0.f);

    #pragma unroll 2
    for (int it = 0; it < (RPB / 4) / 4; ++it) {
        const int r = wbeg + it * 4;
        if (r >= M) break;
        const size_t base = (size_t)r * 64 + lane;
        const float4 w4 = W4[r >> 2];          // wave-uniform broadcast
        float4 v0 = ntload4(&V4[base]);
        float4 v1 = ntload4(&V4[base + 64]);
        float4 v2 = ntload4(&V4[base + 128]);
        float4 v3 = ntload4(&V4[base + 192]);

        acc.x += w4.x*v0.x + w4.y*v1.x + w4.z*v2.x + w4.w*v3.x;
        acc.y += w4.x*v0.y + w4.y*v1.y + w4.z*v2.y + w4.w*v3.y;
        acc.z += w4.x*v0.z + w4.y*v1.z + w4.z*v2.z + w4.w*v3.z;
        acc.w += w4.x*v0.w + w4.y*v1.w + w4.z*v2.w + w4.w*v3.w;
    }

    s_acc[wave][lane] = acc;
    __syncthreads();
    float yv = 0.f;
    const float* saf = (const float*)&s_acc[0][0];
    #pragma unroll
    for (int ww = 0; ww < 4; ++ww) yv += saf[ww * DVD + t];
    partT[(size_t)t * NB + b] = yv;            // contiguous for kernel D
}

// ---- Kernel D: out[j] = (sum_b partT[j][b]) / L ----
__global__ __launch_bounds__(TPB) void k_combine(
    const float* __restrict__ partT,
    const float* __restrict__ psum,
    float* __restrict__ out)
{
    __shared__ float red[TPB];
    const int t = threadIdx.x;

    float ls = (t < RED_B) ? psum[t] : 0.f;
    red[t] = ls; __syncthreads();
    for (int s = TPB / 2; s > 0; s >>= 1) {
        if (t < s) red[t] += red[t + s];
        __syncthreads();
    }
    const float invL = 1.0f / red[0];
    __syncthreads();

    const int j = blockIdx.x;
    const float4* P4 = (const float4*)(partT + (size_t)j * NB);
    float part = 0.f;
    const float4 v = P4[t];                    // NB/4 == TPB
    part = v.x + v.y + v.z + v.w;
    red[t] = part; __syncthreads();
    for (int s = TPB / 2; s > 0; s >>= 1) {
        if (t < s) red[t] += red[t + s];
        __syncthreads();
    }
    if (t == 0) out[j] = red[0] * invL;
}

extern "C" void kernel_launch(void* const* d_in, const int* in_sizes, int n_in,
                              void* d_out, int out_size, void* d_ws, size_t ws_size,
                              hipStream_t stream) {
    const float* q = (const float*)d_in[0];
    const float* K = (const float*)d_in[1];
    const float* V = (const float*)d_in[2];
    float* out = (float*)d_out;

    const int M = in_sizes[1] / DKD;   // 131072

    // ws: logits[M] | w[M] | partT[DVD*NB] | pmax[RED_B] | psum[RED_B]
    float* ws     = (float*)d_ws;
    float* logits = ws;
    float* w      = logits + M;
    float* partT  = w + M;
    float* pmax   = partT + (size_t)DVD * NB;
    float* psum   = pmax + RED_B;

    k_logits <<<NB,    TPB, 0, stream>>>(q, K, logits, M);
    k_max    <<<RED_B, TPB, 0, stream>>>(logits, pmax, M);
    k_expsum <<<RED_B, TPB, 0, stream>>>(logits, pmax, w, psum, M);
    k_vacc   <<<NB,    TPB, 0, stream>>>(V, w, partT, M);
    k_combine<<<DVD,   TPB, 0, stream>>>(partT, psum, out);
}